// Round 5
// baseline (152.050 us; speedup 1.0000x reference)
//
#include <hip/hip_runtime.h>

#define POOL    7
#define RSTRIDE 16.0f
#define IMG_H   128
#define IMG_W   128
#define IMG_C   512
#define C4      (IMG_C / 4)   // float4s per pixel
#define NBINS   64            // 8x8 Morton grid

typedef float f4v __attribute__((ext_vector_type(4)));

__device__ __forceinline__ int roi_bin(const float* __restrict__ roi, int i) {
    const float x = roi[i * 4 + 0];
    const float y = roi[i * 4 + 1];
    const int cx = (int)fminf(fmaxf(x * (1.0f / RSTRIDE), 0.0f), 127.0f);
    const int cy = (int)fminf(fmaxf(y * (1.0f / RSTRIDE), 0.0f), 127.0f);
    const int bx = cx >> 4, by = cy >> 4;
    return (by & 1) | ((bx & 1) << 1) | ((by & 2) << 1) |
           ((bx & 2) << 2) | ((by & 4) << 2) | ((bx & 4) << 3);
}

// Lean one-block counting sort of RoI indices by Morton bin (N<=1024: one
// item per thread; LDS histogram; wave-0 shuffle exclusive-scan over 64 bins;
// scatter). Output order is used only for locality -> any within-bin
// permutation is fine; final output is keyed by RoI index (deterministic).
__global__ __launch_bounds__(1024)
void roi_sort_kernel(const float* __restrict__ roi, int N, int* __restrict__ order)
{
    __shared__ int cnt[NBINS];
    const int t = threadIdx.x;
    if (t < NBINS) cnt[t] = 0;
    __syncthreads();
    int mybin = -1;
    if (t < N) { mybin = roi_bin(roi, t); atomicAdd(&cnt[mybin], 1); }
    __syncthreads();
    if (t < 64) {                    // wave 0: exclusive scan over 64 bins
        int v = cnt[t];
        int s = v;
        #pragma unroll
        for (int d = 1; d < 64; d <<= 1) {
            int up = __shfl_up(s, d, 64);
            if ((t & 63) >= d) s += up;
        }
        cnt[t] = s - v;              // exclusive prefix
    }
    __syncthreads();
    if (t < N) {
        const int p = atomicAdd(&cnt[mybin], 1);
        order[p] = t;
    }
}

// One block (128 threads) per output row (n, py). XCD x = blockIdx%8 walks a
// contiguous slice of the Morton-sorted RoI list -> concurrently resident
// RoIs on one XCD overlap spatially (small L2 working set). Loads issued in
// batches of 16/12 for MLP depth. Normal (cached) stores.
template <bool SORT>
__global__ __launch_bounds__(128)
void roi_pool_kernel(const float* __restrict__ image,
                     const float* __restrict__ roi,
                     float* __restrict__ out, int N,
                     const int* __restrict__ order)
{
    int n, py;
    if (SORT) {
        const int xcd = blockIdx.x & 7;
        const int j   = blockIdx.x >> 3;      // 0 .. N*7/8 - 1
        const int q   = j / POOL;
        py = j - q * POOL;
        n  = order[xcd * (N >> 3) + q];
    } else {
        n  = blockIdx.x / POOL;
        py = blockIdx.x - n * POOL;
    }

    // RoI scalar math (uniform per block -> SGPRs)
    const float x = roi[n * 4 + 0];
    const float y = roi[n * 4 + 1];
    const float w = roi[n * 4 + 2];
    const float h = roi[n * 4 + 3];

    const float r  = rintf((x - 0.5f * w) / RSTRIDE);
    const float c  = rintf((y - 0.5f * h) / RSTRIDE);
    const float wq = fmaxf(rintf(w / RSTRIDE), 1.0f);
    const float hq = fmaxf(rintf(h / RSTRIDE), 1.0f);

    float sy = (((float)py + 0.5f) / (float)POOL) * hq - 0.5f;
    sy = fminf(fmaxf(sy, 0.0f), hq - 1.0f);
    const float fy0 = floorf(sy);
    const float ly  = sy - fy0;
    const float fy1 = fminf(fy0 + 1.0f, hq - 1.0f);
    const int iy0 = (int)fminf(fmaxf(c + fy0, 0.0f), (float)(IMG_H - 1));
    const int iy1 = (int)fminf(fmaxf(c + fy1, 0.0f), (float)(IMG_H - 1));

    int   ix0[POOL], ix1[POOL];
    float w00[POOL], w01[POOL], w10[POOL], w11[POOL];
#pragma unroll
    for (int px = 0; px < POOL; ++px) {
        float sx = (((float)px + 0.5f) / (float)POOL) * wq - 0.5f;
        sx = fminf(fmaxf(sx, 0.0f), wq - 1.0f);
        const float fx0 = floorf(sx);
        const float lx  = sx - fx0;
        const float fx1 = fminf(fx0 + 1.0f, wq - 1.0f);
        ix0[px] = (int)fminf(fmaxf(r + fx0, 0.0f), (float)(IMG_W - 1)) * C4;
        ix1[px] = (int)fminf(fmaxf(r + fx1, 0.0f), (float)(IMG_W - 1)) * C4;
        w00[px] = (1.0f - ly) * (1.0f - lx);
        w01[px] = (1.0f - ly) * lx;
        w10[px] = ly * (1.0f - lx);
        w11[px] = ly * lx;
    }

    const int t = threadIdx.x;                 // channel group 0..127
    const f4v* row0 = (const f4v*)(image + (size_t)iy0 * IMG_W * IMG_C) + t;
    const f4v* row1 = (const f4v*)(image + (size_t)iy1 * IMG_W * IMG_C) + t;
    f4v* po = (f4v*)(out + ((size_t)n * (POOL * POOL) + (size_t)py * POOL) * IMG_C) + t;

    {   // px 0..3: 16 loads in flight
        f4v A[4], B[4], C[4], D[4];
#pragma unroll
        for (int i = 0; i < 4; ++i) {
            A[i] = row0[ix0[i]];
            B[i] = row0[ix1[i]];
            C[i] = row1[ix0[i]];
            D[i] = row1[ix1[i]];
        }
#pragma unroll
        for (int i = 0; i < 4; ++i)
            po[i * C4] = w00[i] * A[i] + w01[i] * B[i] + w10[i] * C[i] + w11[i] * D[i];
    }
    {   // px 4..6: 12 loads in flight
        f4v A[3], B[3], C[3], D[3];
#pragma unroll
        for (int i = 0; i < 3; ++i) {
            A[i] = row0[ix0[4 + i]];
            B[i] = row0[ix1[4 + i]];
            C[i] = row1[ix0[4 + i]];
            D[i] = row1[ix1[4 + i]];
        }
#pragma unroll
        for (int i = 0; i < 3; ++i)
            po[(4 + i) * C4] = w00[4 + i] * A[i] + w01[4 + i] * B[i] +
                               w10[4 + i] * C[i] + w11[4 + i] * D[i];
    }
}

extern "C" void kernel_launch(void* const* d_in, const int* in_sizes, int n_in,
                              void* d_out, int out_size, void* d_ws, size_t ws_size,
                              hipStream_t stream)
{
    const float* image = (const float*)d_in[0];   // (1,128,128,512) fp32
    const float* roi   = (const float*)d_in[1];   // (N,4) fp32
    float*       out   = (float*)d_out;           // (1,N,7,7,512) fp32

    const int N = in_sizes[1] / 4;                // 1000
    const int blocks = N * POOL;                  // 7000 row-blocks
    int* order = (int*)d_ws;

    const bool sortable = ((N & 7) == 0) && N <= 1024 &&
                          ws_size >= (size_t)N * sizeof(int);
    if (sortable) {
        roi_sort_kernel<<<1, 1024, 0, stream>>>(roi, N, order);
        roi_pool_kernel<true><<<blocks, 128, 0, stream>>>(image, roi, out, N, order);
    } else {
        roi_pool_kernel<false><<<blocks, 128, 0, stream>>>(image, roi, out, N, order);
    }
}